// Round 1
// baseline (2375.287 us; speedup 1.0000x reference)
//
#include <hip/hip_runtime.h>

#define N_NODES 100000
#define N_EDGES 1600000
#define HID 128
#define N_LAYERS 4
#define EPSV 1e-5f

// ---------------- degree + norm ----------------
__global__ __launch_bounds__(256) void k_degrees(const int* __restrict__ src, const int* __restrict__ dst,
                                                 int* __restrict__ deg_out, int* __restrict__ deg_in) {
  int i = blockIdx.x * 256 + threadIdx.x;
  if (i < N_EDGES) {
    atomicAdd(&deg_out[src[i]], 1);
    atomicAdd(&deg_in[dst[i]], 1);
  }
}

__global__ __launch_bounds__(256) void k_norms(const int* __restrict__ deg_out, const int* __restrict__ deg_in,
                                               float* __restrict__ norm_src, float* __restrict__ norm_dst) {
  int i = blockIdx.x * 256 + threadIdx.x;
  if (i < N_NODES) {
    int d_o = deg_out[i], d_i = deg_in[i];
    norm_src[i] = d_o > 0 ? rsqrtf((float)d_o) : 0.f;
    norm_dst[i] = d_i > 0 ? rsqrtf((float)d_i) : 0.f;
  }
}

// ---------------- exclusive scan (single block, 1024 threads) ----------------
__global__ __launch_bounds__(1024) void k_scan(const int* __restrict__ in, int* __restrict__ out) {
  __shared__ int wsum[16];
  __shared__ int carry_s;
  const int n = N_NODES;
  int tid = threadIdx.x, lane = tid & 63, wid = tid >> 6;
  if (tid == 0) carry_s = 0;
  __syncthreads();
  for (int base = 0; base < n; base += 1024) {
    int i = base + tid;
    int orig = (i < n) ? in[i] : 0;
    int v = orig;
#pragma unroll
    for (int off = 1; off < 64; off <<= 1) {
      int u = __shfl_up(v, off, 64);
      if (lane >= off) v += u;
    }
    if (lane == 63) wsum[wid] = v;
    __syncthreads();
    if (wid == 0) {
      int s = (lane < 16) ? wsum[lane] : 0;
#pragma unroll
      for (int off = 1; off < 16; off <<= 1) {
        int u = __shfl_up(s, off, 64);
        if (lane >= off) s += u;
      }
      if (lane < 16) wsum[lane] = s;
    }
    __syncthreads();
    int carry = carry_s;
    int woff = (wid > 0) ? wsum[wid - 1] : 0;
    int incl = v + woff + carry;
    if (i < n) out[i] = incl - orig;
    __syncthreads();
    if (tid == 1023) carry_s = incl;
    __syncthreads();
  }
  if (threadIdx.x == 0) out[n] = carry_s;
}

// ---------------- CSR fill ----------------
__global__ __launch_bounds__(256) void k_fill_csr(const int* __restrict__ src, const int* __restrict__ dst,
                                                  int* __restrict__ cursor, int* __restrict__ csr_src) {
  int i = blockIdx.x * 256 + threadIdx.x;
  if (i < N_EDGES) {
    int d = dst[i];
    int pos = atomicAdd(&cursor[d], 1);
    csr_src[pos] = src[i];
  }
}

// ---------------- embedding lookup ----------------
__global__ __launch_bounds__(256) void k_embed(const int* __restrict__ h, const float* __restrict__ emb,
                                               float* __restrict__ x) {
  int i = blockIdx.x * 256 + threadIdx.x;  // over N*32 float4
  const int total = N_NODES * (HID / 4);
  if (i < total) {
    int r = i >> 5, c = i & 31;
    ((float4*)x)[i] = ((const float4*)emb)[h[r] * (HID / 4) + c];
  }
}

// ---------------- aggregation: agg[n] = norm_dst[n] * sum_{s in N(n)} x[s]*norm_src[s] ----------------
__global__ __launch_bounds__(256) void k_agg(const float* __restrict__ x, const int* __restrict__ row_ptr,
                                             const int* __restrict__ csr_src, const float* __restrict__ norm_src,
                                             const float* __restrict__ norm_dst, float* __restrict__ agg) {
  int node = blockIdx.x * 8 + (threadIdx.x >> 5);
  int l32 = threadIdx.x & 31;
  if (node >= N_NODES) return;
  int s0 = row_ptr[node], s1 = row_ptr[node + 1];
  float4 acc = {0.f, 0.f, 0.f, 0.f};
  for (int i = s0; i < s1; ++i) {
    int s = csr_src[i];
    float ns = norm_src[s];
    float4 v = ((const float4*)(x + (size_t)s * HID))[l32];
    acc.x += v.x * ns; acc.y += v.y * ns; acc.z += v.z * ns; acc.w += v.w * ns;
  }
  float nd = norm_dst[node];
  acc.x *= nd; acc.y *= nd; acc.z *= nd; acc.w *= nd;
  ((float4*)(agg + (size_t)node * HID))[l32] = acc;
}

// ---------------- GEMM [N,128]x[128,128] + bias, in-place capable, fused BN stats ----------------
__global__ __launch_bounds__(256) void k_gemm_stats(const float* __restrict__ A, const float* __restrict__ W,
                                                    const float* __restrict__ bias, float* __restrict__ Y,
                                                    float* __restrict__ sums, float* __restrict__ sumsq) {
  __shared__ float As[64][132];
  __shared__ float Ws[128][128];
  __shared__ float red[16][128];
  int tid = threadIdx.x;
  // stage W (16384 floats = 4096 float4)
  for (int i = tid; i < 4096; i += 256) ((float4*)Ws)[i] = ((const float4*)W)[i];
  int row0 = blockIdx.x * 64;
  // stage A tile (64x128 = 2048 float4), zero-pad past N
  for (int i = tid; i < 2048; i += 256) {
    int r = i >> 5, c4 = i & 31;
    float4 v = {0.f, 0.f, 0.f, 0.f};
    if (row0 + r < N_NODES) v = ((const float4*)(A + (size_t)(row0 + r) * HID))[c4];
    *(float4*)&As[r][c4 * 4] = v;
  }
  int tx = tid & 15, ty = tid >> 4;
  int r0 = ty * 4, c0 = tx * 8;
  float acc[4][8];
#pragma unroll
  for (int i = 0; i < 4; ++i)
#pragma unroll
    for (int j = 0; j < 8; ++j) acc[i][j] = 0.f;
  __syncthreads();
  for (int k = 0; k < 128; ++k) {
    float a[4];
#pragma unroll
    for (int i = 0; i < 4; ++i) a[i] = As[r0 + i][k];
    float4 w0 = *(const float4*)&Ws[k][c0];
    float4 w1 = *(const float4*)&Ws[k][c0 + 4];
    float w[8] = {w0.x, w0.y, w0.z, w0.w, w1.x, w1.y, w1.z, w1.w};
#pragma unroll
    for (int i = 0; i < 4; ++i)
#pragma unroll
      for (int j = 0; j < 8; ++j) acc[i][j] += a[i] * w[j];
  }
  float bv[8];
#pragma unroll
  for (int j = 0; j < 8; ++j) bv[j] = bias[c0 + j];
  float s[8], q[8];
#pragma unroll
  for (int j = 0; j < 8; ++j) { s[j] = 0.f; q[j] = 0.f; }
#pragma unroll
  for (int i = 0; i < 4; ++i) {
    int r = row0 + r0 + i;
    if (r < N_NODES) {
      float yv[8];
#pragma unroll
      for (int j = 0; j < 8; ++j) {
        yv[j] = acc[i][j] + bv[j];
        s[j] += yv[j];
        q[j] += yv[j] * yv[j];
      }
      float4 o0 = {yv[0], yv[1], yv[2], yv[3]};
      float4 o1 = {yv[4], yv[5], yv[6], yv[7]};
      float4* yp = (float4*)(Y + (size_t)r * HID + c0);
      yp[0] = o0;
      yp[1] = o1;
    }
  }
  // block-level column reduction: sums
#pragma unroll
  for (int j = 0; j < 8; ++j) red[ty][c0 + j] = s[j];
  __syncthreads();
  for (int hh = 8; hh >= 1; hh >>= 1) {
    if (ty < hh) {
#pragma unroll
      for (int j = 0; j < 8; ++j) red[ty][c0 + j] += red[ty + hh][c0 + j];
    }
    __syncthreads();
  }
  if (ty == 0) {
#pragma unroll
    for (int j = 0; j < 8; ++j) atomicAdd(&sums[c0 + j], red[0][c0 + j]);
  }
  __syncthreads();
#pragma unroll
  for (int j = 0; j < 8; ++j) red[ty][c0 + j] = q[j];
  __syncthreads();
  for (int hh = 8; hh >= 1; hh >>= 1) {
    if (ty < hh) {
#pragma unroll
      for (int j = 0; j < 8; ++j) red[ty][c0 + j] += red[ty + hh][c0 + j];
    }
    __syncthreads();
  }
  if (ty == 0) {
#pragma unroll
    for (int j = 0; j < 8; ++j) atomicAdd(&sumsq[c0 + j], red[0][c0 + j]);
  }
}

// ---------------- BN finalize ----------------
__global__ __launch_bounds__(128) void k_bn_final(const float* __restrict__ sums, const float* __restrict__ sumsq,
                                                  const float* __restrict__ gamma, const float* __restrict__ beta,
                                                  float* __restrict__ scale, float* __restrict__ shift) {
  int d = threadIdx.x;
  float mu = sums[d] / (float)N_NODES;
  float var = sumsq[d] / (float)N_NODES - mu * mu;
  float sc = gamma[d] * rsqrtf(var + EPSV);
  scale[d] = sc;
  shift[d] = beta[d] - mu * sc;
}

// ---------------- BN apply + relu + residual (x updated in place) ----------------
__global__ __launch_bounds__(256) void k_bn_apply(const float* __restrict__ Y, const float* __restrict__ scale,
                                                  const float* __restrict__ shift, float* __restrict__ x) {
  int i = blockIdx.x * 256 + threadIdx.x;  // over N*32 float4
  const int total = N_NODES * (HID / 4);
  if (i >= total) return;
  int c4 = i & 31;
  float4 y = ((const float4*)Y)[i];
  float4 sc = ((const float4*)scale)[c4];
  float4 sh = ((const float4*)shift)[c4];
  float4 xv = ((const float4*)x)[i];
  float4 o;
  o.x = fmaxf(y.x * sc.x + sh.x, 0.f) + xv.x;
  o.y = fmaxf(y.y * sc.y + sh.y, 0.f) + xv.y;
  o.z = fmaxf(y.z * sc.z + sh.z, 0.f) + xv.z;
  o.w = fmaxf(y.w * sc.w + sh.w, 0.f) + xv.w;
  ((float4*)x)[i] = o;
}

// ---------------- small dense layers (thread-per-row) ----------------
template <int K, int NOUT, bool RELU>
__global__ __launch_bounds__(256) void k_mlp(const float* __restrict__ X, const float* __restrict__ Wm,
                                             const float* __restrict__ bias, float* __restrict__ Y) {
  __shared__ float Ws[K * NOUT];
  __shared__ float bs[NOUT];
  for (int i = threadIdx.x; i < K * NOUT; i += 256) Ws[i] = Wm[i];
  for (int i = threadIdx.x; i < NOUT; i += 256) bs[i] = bias[i];
  __syncthreads();
  int r = blockIdx.x * 256 + threadIdx.x;
  if (r >= N_NODES) return;
  const float4* xr = (const float4*)(X + (size_t)r * K);
  float acc[NOUT];
#pragma unroll
  for (int c = 0; c < NOUT; ++c) acc[c] = bs[c];
  for (int k4 = 0; k4 < K / 4; ++k4) {
    float4 xv = xr[k4];
    float xs[4] = {xv.x, xv.y, xv.z, xv.w};
#pragma unroll
    for (int kk = 0; kk < 4; ++kk) {
#pragma unroll
      for (int c = 0; c < NOUT; ++c) acc[c] += xs[kk] * Ws[(k4 * 4 + kk) * NOUT + c];
    }
  }
  float* yr = Y + (size_t)r * NOUT;
#pragma unroll
  for (int c = 0; c < NOUT; ++c) yr[c] = RELU ? fmaxf(acc[c], 0.f) : acc[c];
}

extern "C" void kernel_launch(void* const* d_in, const int* in_sizes, int n_in,
                              void* d_out, int out_size, void* d_ws, size_t ws_size,
                              hipStream_t stream) {
  const int* h = (const int*)d_in[0];
  const int* src = (const int*)d_in[1];
  const int* dst = (const int*)d_in[2];
  const float* emb = (const float*)d_in[3];
  const float* W = (const float*)d_in[4];
  const float* b = (const float*)d_in[5];
  const float* gamma = (const float*)d_in[6];
  const float* beta = (const float*)d_in[7];
  const float* W1 = (const float*)d_in[8];
  const float* b1 = (const float*)d_in[9];
  const float* W2 = (const float*)d_in[10];
  const float* b2 = (const float*)d_in[11];
  const float* W3 = (const float*)d_in[12];
  const float* b3 = (const float*)d_in[13];
  float* out = (float*)d_out;

  char* ws = (char*)d_ws;
  size_t off = 0;
  auto alloc = [&](size_t bytes) -> void* {
    void* p = ws + off;
    off += (bytes + 255) & ~(size_t)255;
    return p;
  };
  int* deg_out = (int*)alloc(N_NODES * 4);
  int* deg_in = (int*)alloc(N_NODES * 4);
  float* norm_src = (float*)alloc(N_NODES * 4);
  float* norm_dst = (float*)alloc(N_NODES * 4);
  int* row_ptr = (int*)alloc((N_NODES + 1) * 4);
  int* cursor = (int*)alloc(N_NODES * 4);
  int* csr_src = (int*)alloc((size_t)N_EDGES * 4);
  float* x = (float*)alloc((size_t)N_NODES * HID * 4);
  float* agg = (float*)alloc((size_t)N_NODES * HID * 4);
  float* sums = (float*)alloc(512);
  float* sumsq = (float*)alloc(512);
  float* scale = (float*)alloc(512);
  float* shift = (float*)alloc(512);
  float* y1 = agg;                          // [N,64] reuse (agg dead after layers)
  float* y2 = agg + (size_t)N_NODES * 64;   // [N,32]

  hipMemsetAsync(deg_out, 0, N_NODES * 4, stream);
  hipMemsetAsync(deg_in, 0, N_NODES * 4, stream);
  k_degrees<<<(N_EDGES + 255) / 256, 256, 0, stream>>>(src, dst, deg_out, deg_in);
  k_norms<<<(N_NODES + 255) / 256, 256, 0, stream>>>(deg_out, deg_in, norm_src, norm_dst);
  k_scan<<<1, 1024, 0, stream>>>(deg_in, row_ptr);
  hipMemcpyAsync(cursor, row_ptr, N_NODES * 4, hipMemcpyDeviceToDevice, stream);
  k_fill_csr<<<(N_EDGES + 255) / 256, 256, 0, stream>>>(src, dst, cursor, csr_src);
  k_embed<<<(N_NODES * (HID / 4) + 255) / 256, 256, 0, stream>>>(h, emb, x);

  for (int l = 0; l < N_LAYERS; ++l) {
    k_agg<<<(N_NODES + 7) / 8, 256, 0, stream>>>(x, row_ptr, csr_src, norm_src, norm_dst, agg);
    hipMemsetAsync(sums, 0, 1024, stream);  // sums + sumsq are contiguous (512B each, 256B-aligned alloc)
    k_gemm_stats<<<(N_NODES + 63) / 64, 256, 0, stream>>>(agg, W + (size_t)l * HID * HID, b + l * HID,
                                                          agg, sums, sumsq);
    k_bn_final<<<1, 128, 0, stream>>>(sums, sumsq, gamma + l * HID, beta + l * HID, scale, shift);
    k_bn_apply<<<(N_NODES * (HID / 4) + 255) / 256, 256, 0, stream>>>(agg, scale, shift, x);
  }

  k_mlp<128, 64, true><<<(N_NODES + 255) / 256, 256, 0, stream>>>(x, W1, b1, y1);
  k_mlp<64, 32, true><<<(N_NODES + 255) / 256, 256, 0, stream>>>(y1, W2, b2, y2);
  k_mlp<32, 6, false><<<(N_NODES + 255) / 256, 256, 0, stream>>>(y2, W3, b3, out);
}

// Round 2
// 1464.855 us; speedup vs baseline: 1.6215x; 1.6215x over previous
//
#include <hip/hip_runtime.h>

#define N_NODES 100000
#define N_EDGES 1600000
#define HID 128
#define N_LAYERS 4
#define EPSV 1e-5f

// ---------------- degree + norm ----------------
__global__ __launch_bounds__(256) void k_degrees(const int* __restrict__ src, const int* __restrict__ dst,
                                                 int* __restrict__ deg_out, int* __restrict__ deg_in) {
  int i = blockIdx.x * 256 + threadIdx.x;
  if (i < N_EDGES) {
    atomicAdd(&deg_out[src[i]], 1);
    atomicAdd(&deg_in[dst[i]], 1);
  }
}

__global__ __launch_bounds__(256) void k_norms(const int* __restrict__ deg_out, const int* __restrict__ deg_in,
                                               float* __restrict__ norm_src, float* __restrict__ norm_dst) {
  int i = blockIdx.x * 256 + threadIdx.x;
  if (i < N_NODES) {
    int d_o = deg_out[i], d_i = deg_in[i];
    norm_src[i] = d_o > 0 ? rsqrtf((float)d_o) : 0.f;
    norm_dst[i] = d_i > 0 ? rsqrtf((float)d_i) : 0.f;
  }
}

// ---------------- exclusive scan (single block, 1024 threads) ----------------
__global__ __launch_bounds__(1024) void k_scan(const int* __restrict__ in, int* __restrict__ out) {
  __shared__ int wsum[16];
  __shared__ int carry_s;
  const int n = N_NODES;
  int tid = threadIdx.x, lane = tid & 63, wid = tid >> 6;
  if (tid == 0) carry_s = 0;
  __syncthreads();
  for (int base = 0; base < n; base += 1024) {
    int i = base + tid;
    int orig = (i < n) ? in[i] : 0;
    int v = orig;
#pragma unroll
    for (int off = 1; off < 64; off <<= 1) {
      int u = __shfl_up(v, off, 64);
      if (lane >= off) v += u;
    }
    if (lane == 63) wsum[wid] = v;
    __syncthreads();
    if (wid == 0) {
      int s = (lane < 16) ? wsum[lane] : 0;
#pragma unroll
      for (int off = 1; off < 16; off <<= 1) {
        int u = __shfl_up(s, off, 64);
        if (lane >= off) s += u;
      }
      if (lane < 16) wsum[lane] = s;
    }
    __syncthreads();
    int carry = carry_s;
    int woff = (wid > 0) ? wsum[wid - 1] : 0;
    int incl = v + woff + carry;
    if (i < n) out[i] = incl - orig;
    __syncthreads();
    if (tid == 1023) carry_s = incl;
    __syncthreads();
  }
  if (threadIdx.x == 0) out[n] = carry_s;
}

// ---------------- CSR fill ----------------
__global__ __launch_bounds__(256) void k_fill_csr(const int* __restrict__ src, const int* __restrict__ dst,
                                                  int* __restrict__ cursor, int* __restrict__ csr_src) {
  int i = blockIdx.x * 256 + threadIdx.x;
  if (i < N_EDGES) {
    int d = dst[i];
    int pos = atomicAdd(&cursor[d], 1);
    csr_src[pos] = src[i];
  }
}

// ---------------- embedding lookup ----------------
__global__ __launch_bounds__(256) void k_embed(const int* __restrict__ h, const float* __restrict__ emb,
                                               float* __restrict__ x) {
  int i = blockIdx.x * 256 + threadIdx.x;  // over N*32 float4
  const int total = N_NODES * (HID / 4);
  if (i < total) {
    int r = i >> 5, c = i & 31;
    ((float4*)x)[i] = ((const float4*)emb)[h[r] * (HID / 4) + c];
  }
}

// ---------------- aggregation: agg[n] = norm_dst[n] * sum_{s in N(n)} x[s]*norm_src[s] ----------------
// 16 lanes per node, 2 float4 per lane, edge loop unrolled x2 -> 4 independent 16B loads in flight
__global__ __launch_bounds__(256) void k_agg(const float* __restrict__ x, const int* __restrict__ row_ptr,
                                             const int* __restrict__ csr_src, const float* __restrict__ norm_src,
                                             const float* __restrict__ norm_dst, float* __restrict__ agg) {
  int node = blockIdx.x * 16 + (threadIdx.x >> 4);
  int l16 = threadIdx.x & 15;
  if (node >= N_NODES) return;
  int s0 = row_ptr[node], s1 = row_ptr[node + 1];
  float ax = 0.f, ay = 0.f, az = 0.f, aw = 0.f;
  float bx = 0.f, by = 0.f, bz = 0.f, bw = 0.f;
  int i = s0;
  for (; i + 1 < s1; i += 2) {
    int sa = csr_src[i], sb = csr_src[i + 1];
    float na = norm_src[sa], nb = norm_src[sb];
    const float4* pa = (const float4*)(x + (size_t)sa * HID);
    const float4* pb = (const float4*)(x + (size_t)sb * HID);
    float4 va0 = pa[l16], va1 = pa[l16 + 16];
    float4 vb0 = pb[l16], vb1 = pb[l16 + 16];
    ax += va0.x * na + vb0.x * nb; ay += va0.y * na + vb0.y * nb;
    az += va0.z * na + vb0.z * nb; aw += va0.w * na + vb0.w * nb;
    bx += va1.x * na + vb1.x * nb; by += va1.y * na + vb1.y * nb;
    bz += va1.z * na + vb1.z * nb; bw += va1.w * na + vb1.w * nb;
  }
  if (i < s1) {
    int sa = csr_src[i];
    float na = norm_src[sa];
    const float4* pa = (const float4*)(x + (size_t)sa * HID);
    float4 va0 = pa[l16], va1 = pa[l16 + 16];
    ax += va0.x * na; ay += va0.y * na; az += va0.z * na; aw += va0.w * na;
    bx += va1.x * na; by += va1.y * na; bz += va1.z * na; bw += va1.w * na;
  }
  float nd = norm_dst[node];
  float4 o0 = {ax * nd, ay * nd, az * nd, aw * nd};
  float4 o1 = {bx * nd, by * nd, bz * nd, bw * nd};
  float4* op = (float4*)(agg + (size_t)node * HID);
  op[l16] = o0;
  op[l16 + 16] = o1;
}

// ---------------- GEMM [N,128]x[128,128] + bias + fused BN stats ----------------
// 128x128 tile per block, K-step 32. LDS: Ast[32][132] (A^T) + Ws[32][128] = 33 KB -> 4 blocks/CU.
// Thread (tr,tc) owns rows {tr*4+i, 64+tr*4+i} x cols {tc*4+j, 64+tc*4+j}. All LDS reads <=2-way conflict.
__global__ __launch_bounds__(256, 4) void k_gemm_stats(const float* __restrict__ A, const float* __restrict__ W,
                                                       const float* __restrict__ bias, float* __restrict__ Y,
                                                       float* __restrict__ sums, float* __restrict__ sumsq) {
  __shared__ float smem[32 * 132 + 32 * 128];  // 33792 B
  float* sA = smem;            // Ast[kk][row], stride 132
  float* sW = smem + 32 * 132; // Ws[kk][col], stride 128
  const int tid = threadIdx.x;
  const int tc = tid & 15, tr = tid >> 4;
  const int row0 = blockIdx.x * 128;

  float acc[8][8];
#pragma unroll
  for (int i = 0; i < 8; ++i)
#pragma unroll
    for (int j = 0; j < 8; ++j) acc[i][j] = 0.f;

  for (int kb = 0; kb < 4; ++kb) {
    // stage A^T tile: 128 rows x 32 k  (1024 float4 loads, transpose-store)
#pragma unroll
    for (int it = 0; it < 4; ++it) {
      int idx = tid + it * 256;       // 0..1023
      int r = idx >> 3, c4 = idx & 7; // row, k-float4
      float4 v = {0.f, 0.f, 0.f, 0.f};
      if (row0 + r < N_NODES) v = *(const float4*)(A + (size_t)(row0 + r) * HID + kb * 32 + c4 * 4);
      sA[(c4 * 4 + 0) * 132 + r] = v.x;
      sA[(c4 * 4 + 1) * 132 + r] = v.y;
      sA[(c4 * 4 + 2) * 132 + r] = v.z;
      sA[(c4 * 4 + 3) * 132 + r] = v.w;
    }
    // stage W tile: 32 k x 128 cols (contiguous copy)
#pragma unroll
    for (int it = 0; it < 4; ++it) {
      int idx = tid + it * 256;       // 0..1023
      int kk = idx >> 5, c4 = idx & 31;
      *(float4*)(sW + kk * 128 + c4 * 4) = *(const float4*)(W + (size_t)(kb * 32 + kk) * HID + c4 * 4);
    }
    __syncthreads();
#pragma unroll 8
    for (int kk = 0; kk < 32; ++kk) {
      float4 a0 = *(const float4*)(sA + kk * 132 + tr * 4);
      float4 a1 = *(const float4*)(sA + kk * 132 + 64 + tr * 4);
      float4 w0 = *(const float4*)(sW + kk * 128 + tc * 4);
      float4 w1 = *(const float4*)(sW + kk * 128 + 64 + tc * 4);
      float a[8] = {a0.x, a0.y, a0.z, a0.w, a1.x, a1.y, a1.z, a1.w};
      float w[8] = {w0.x, w0.y, w0.z, w0.w, w1.x, w1.y, w1.z, w1.w};
#pragma unroll
      for (int i = 0; i < 8; ++i)
#pragma unroll
        for (int j = 0; j < 8; ++j) acc[i][j] += a[i] * w[j];
    }
    __syncthreads();
  }

  // bias + store + per-thread stats
  float bv[8];
#pragma unroll
  for (int j = 0; j < 8; ++j) bv[j] = bias[(j < 4) ? (tc * 4 + j) : (64 + tc * 4 + j - 4)];
  float s[8], q[8];
#pragma unroll
  for (int j = 0; j < 8; ++j) { s[j] = 0.f; q[j] = 0.f; }
#pragma unroll
  for (int i = 0; i < 8; ++i) {
    int r = row0 + ((i < 4) ? (tr * 4 + i) : (64 + tr * 4 + i - 4));
    if (r < N_NODES) {
      float yv[8];
#pragma unroll
      for (int j = 0; j < 8; ++j) {
        yv[j] = acc[i][j] + bv[j];
        s[j] += yv[j];
        q[j] += yv[j] * yv[j];
      }
      float4* yp0 = (float4*)(Y + (size_t)r * HID + tc * 4);
      float4* yp1 = (float4*)(Y + (size_t)r * HID + 64 + tc * 4);
      *yp0 = make_float4(yv[0], yv[1], yv[2], yv[3]);
      *yp1 = make_float4(yv[4], yv[5], yv[6], yv[7]);
    }
  }
  // block reduction over tr (reuse LDS)
  __syncthreads();
  float* red_s = smem;          // [16][128]
  float* red_q = smem + 2048;   // [16][128]
#pragma unroll
  for (int j = 0; j < 8; ++j) {
    int c = (j < 4) ? (tc * 4 + j) : (64 + tc * 4 + j - 4);
    red_s[tr * 128 + c] = s[j];
    red_q[tr * 128 + c] = q[j];
  }
  __syncthreads();
  for (int hh = 8; hh >= 1; hh >>= 1) {
    if (tr < hh) {
#pragma unroll
      for (int j = 0; j < 8; ++j) {
        int c = (j < 4) ? (tc * 4 + j) : (64 + tc * 4 + j - 4);
        red_s[tr * 128 + c] += red_s[(tr + hh) * 128 + c];
        red_q[tr * 128 + c] += red_q[(tr + hh) * 128 + c];
      }
    }
    __syncthreads();
  }
  if (tr == 0) {
#pragma unroll
    for (int j = 0; j < 8; ++j) {
      int c = (j < 4) ? (tc * 4 + j) : (64 + tc * 4 + j - 4);
      atomicAdd(&sums[c], red_s[c]);
      atomicAdd(&sumsq[c], red_q[c]);
    }
  }
}

// ---------------- BN finalize ----------------
__global__ __launch_bounds__(128) void k_bn_final(const float* __restrict__ sums, const float* __restrict__ sumsq,
                                                  const float* __restrict__ gamma, const float* __restrict__ beta,
                                                  float* __restrict__ scale, float* __restrict__ shift) {
  int d = threadIdx.x;
  float mu = sums[d] / (float)N_NODES;
  float var = sumsq[d] / (float)N_NODES - mu * mu;
  float sc = gamma[d] * rsqrtf(var + EPSV);
  scale[d] = sc;
  shift[d] = beta[d] - mu * sc;
}

// ---------------- BN apply + relu + residual (x updated in place) ----------------
__global__ __launch_bounds__(256) void k_bn_apply(const float* __restrict__ Y, const float* __restrict__ scale,
                                                  const float* __restrict__ shift, float* __restrict__ x) {
  int i = blockIdx.x * 256 + threadIdx.x;  // over N*32 float4
  const int total = N_NODES * (HID / 4);
  if (i >= total) return;
  int c4 = i & 31;
  float4 y = ((const float4*)Y)[i];
  float4 sc = ((const float4*)scale)[c4];
  float4 sh = ((const float4*)shift)[c4];
  float4 xv = ((const float4*)x)[i];
  float4 o;
  o.x = fmaxf(y.x * sc.x + sh.x, 0.f) + xv.x;
  o.y = fmaxf(y.y * sc.y + sh.y, 0.f) + xv.y;
  o.z = fmaxf(y.z * sc.z + sh.z, 0.f) + xv.z;
  o.w = fmaxf(y.w * sc.w + sh.w, 0.f) + xv.w;
  ((float4*)x)[i] = o;
}

// ---------------- small dense layers (thread-per-row) ----------------
template <int K, int NOUT, bool RELU>
__global__ __launch_bounds__(256) void k_mlp(const float* __restrict__ X, const float* __restrict__ Wm,
                                             const float* __restrict__ bias, float* __restrict__ Y) {
  __shared__ float Ws[K * NOUT];
  __shared__ float bs[NOUT];
  for (int i = threadIdx.x; i < K * NOUT; i += 256) Ws[i] = Wm[i];
  for (int i = threadIdx.x; i < NOUT; i += 256) bs[i] = bias[i];
  __syncthreads();
  int r = blockIdx.x * 256 + threadIdx.x;
  if (r >= N_NODES) return;
  const float4* xr = (const float4*)(X + (size_t)r * K);
  float acc[NOUT];
#pragma unroll
  for (int c = 0; c < NOUT; ++c) acc[c] = bs[c];
  for (int k4 = 0; k4 < K / 4; ++k4) {
    float4 xv = xr[k4];
    float xs[4] = {xv.x, xv.y, xv.z, xv.w};
#pragma unroll
    for (int kk = 0; kk < 4; ++kk) {
#pragma unroll
      for (int c = 0; c < NOUT; ++c) acc[c] += xs[kk] * Ws[(k4 * 4 + kk) * NOUT + c];
    }
  }
  float* yr = Y + (size_t)r * NOUT;
#pragma unroll
  for (int c = 0; c < NOUT; ++c) yr[c] = RELU ? fmaxf(acc[c], 0.f) : acc[c];
}

extern "C" void kernel_launch(void* const* d_in, const int* in_sizes, int n_in,
                              void* d_out, int out_size, void* d_ws, size_t ws_size,
                              hipStream_t stream) {
  const int* h = (const int*)d_in[0];
  const int* src = (const int*)d_in[1];
  const int* dst = (const int*)d_in[2];
  const float* emb = (const float*)d_in[3];
  const float* W = (const float*)d_in[4];
  const float* b = (const float*)d_in[5];
  const float* gamma = (const float*)d_in[6];
  const float* beta = (const float*)d_in[7];
  const float* W1 = (const float*)d_in[8];
  const float* b1 = (const float*)d_in[9];
  const float* W2 = (const float*)d_in[10];
  const float* b2 = (const float*)d_in[11];
  const float* W3 = (const float*)d_in[12];
  const float* b3 = (const float*)d_in[13];
  float* out = (float*)d_out;

  char* ws = (char*)d_ws;
  size_t off = 0;
  auto alloc = [&](size_t bytes) -> void* {
    void* p = ws + off;
    off += (bytes + 255) & ~(size_t)255;
    return p;
  };
  int* deg_out = (int*)alloc(N_NODES * 4);
  int* deg_in = (int*)alloc(N_NODES * 4);
  float* norm_src = (float*)alloc(N_NODES * 4);
  float* norm_dst = (float*)alloc(N_NODES * 4);
  int* row_ptr = (int*)alloc((N_NODES + 1) * 4);
  int* cursor = (int*)alloc(N_NODES * 4);
  int* csr_src = (int*)alloc((size_t)N_EDGES * 4);
  float* x = (float*)alloc((size_t)N_NODES * HID * 4);
  float* agg = (float*)alloc((size_t)N_NODES * HID * 4);
  float* sums = (float*)alloc(512);
  float* sumsq = (float*)alloc(512);
  float* scale = (float*)alloc(512);
  float* shift = (float*)alloc(512);
  float* y1 = agg;                          // [N,64] reuse (agg dead after layers)
  float* y2 = agg + (size_t)N_NODES * 64;   // [N,32]

  hipMemsetAsync(deg_out, 0, N_NODES * 4, stream);
  hipMemsetAsync(deg_in, 0, N_NODES * 4, stream);
  k_degrees<<<(N_EDGES + 255) / 256, 256, 0, stream>>>(src, dst, deg_out, deg_in);
  k_norms<<<(N_NODES + 255) / 256, 256, 0, stream>>>(deg_out, deg_in, norm_src, norm_dst);
  k_scan<<<1, 1024, 0, stream>>>(deg_in, row_ptr);
  hipMemcpyAsync(cursor, row_ptr, N_NODES * 4, hipMemcpyDeviceToDevice, stream);
  k_fill_csr<<<(N_EDGES + 255) / 256, 256, 0, stream>>>(src, dst, cursor, csr_src);
  k_embed<<<(N_NODES * (HID / 4) + 255) / 256, 256, 0, stream>>>(h, emb, x);

  for (int l = 0; l < N_LAYERS; ++l) {
    k_agg<<<(N_NODES + 15) / 16, 256, 0, stream>>>(x, row_ptr, csr_src, norm_src, norm_dst, agg);
    hipMemsetAsync(sums, 0, 1024, stream);  // sums+sumsq contiguous
    k_gemm_stats<<<(N_NODES + 127) / 128, 256, 0, stream>>>(agg, W + (size_t)l * HID * HID, b + l * HID,
                                                            agg, sums, sumsq);
    k_bn_final<<<1, 128, 0, stream>>>(sums, sumsq, gamma + l * HID, beta + l * HID, scale, shift);
    k_bn_apply<<<(N_NODES * (HID / 4) + 255) / 256, 256, 0, stream>>>(agg, scale, shift, x);
  }

  k_mlp<128, 64, true><<<(N_NODES + 255) / 256, 256, 0, stream>>>(x, W1, b1, y1);
  k_mlp<64, 32, true><<<(N_NODES + 255) / 256, 256, 0, stream>>>(y1, W2, b2, y2);
  k_mlp<32, 6, false><<<(N_NODES + 255) / 256, 256, 0, stream>>>(y2, W3, b3, out);
}

// Round 3
// 1374.643 us; speedup vs baseline: 1.7279x; 1.0656x over previous
//
#include <hip/hip_runtime.h>

#define N_NODES 100000
#define N_EDGES 1600000
#define HID 128
#define N_LAYERS 4
#define EPSV 1e-5f
#define SCAN_BLK 98  // ceil(100000/1024)

// ---------------- degree + norm ----------------
__global__ __launch_bounds__(256) void k_degrees(const int* __restrict__ src, const int* __restrict__ dst,
                                                 int* __restrict__ deg_out, int* __restrict__ deg_in) {
  int i = blockIdx.x * 256 + threadIdx.x;
  if (i < N_EDGES) {
    atomicAdd(&deg_out[src[i]], 1);
    atomicAdd(&deg_in[dst[i]], 1);
  }
}

__global__ __launch_bounds__(256) void k_norms(const int* __restrict__ deg_out, const int* __restrict__ deg_in,
                                               float* __restrict__ norm_src, float* __restrict__ norm_dst) {
  int i = blockIdx.x * 256 + threadIdx.x;
  if (i < N_NODES) {
    int d_o = deg_out[i], d_i = deg_in[i];
    norm_src[i] = d_o > 0 ? rsqrtf((float)d_o) : 0.f;
    norm_dst[i] = d_i > 0 ? rsqrtf((float)d_i) : 0.f;
  }
}

// ---------------- 3-kernel exclusive scan ----------------
__global__ __launch_bounds__(256) void k_scan1(const int* __restrict__ in, int* __restrict__ out,
                                               int* __restrict__ partials) {
  __shared__ int wsum[4];
  int tid = threadIdx.x;
  int base = blockIdx.x * 1024 + tid * 4;
  int4 v = {0, 0, 0, 0};
  if (base + 3 < N_NODES) v = *(const int4*)(in + base);
  else {
    if (base + 0 < N_NODES) v.x = in[base + 0];
    if (base + 1 < N_NODES) v.y = in[base + 1];
    if (base + 2 < N_NODES) v.z = in[base + 2];
    if (base + 3 < N_NODES) v.w = in[base + 3];
  }
  int s4 = v.x + v.y + v.z + v.w;
  int lane = tid & 63, wid = tid >> 6;
  int sc = s4;
#pragma unroll
  for (int off = 1; off < 64; off <<= 1) {
    int u = __shfl_up(sc, off, 64);
    if (lane >= off) sc += u;
  }
  if (lane == 63) wsum[wid] = sc;
  __syncthreads();
  int woff = 0;
#pragma unroll
  for (int w = 0; w < 4; ++w) woff += (w < wid) ? wsum[w] : 0;
  int excl = woff + sc - s4;
  int4 o;
  o.x = excl; o.y = o.x + v.x; o.z = o.y + v.y; o.w = o.z + v.z;
  if (base + 3 < N_NODES) *(int4*)(out + base) = o;
  else {
    if (base + 0 < N_NODES) out[base + 0] = o.x;
    if (base + 1 < N_NODES) out[base + 1] = o.y;
    if (base + 2 < N_NODES) out[base + 2] = o.z;
    if (base + 3 < N_NODES) out[base + 3] = o.w;
  }
  if (tid == 255) partials[blockIdx.x] = woff + sc;  // block total
}

__global__ __launch_bounds__(128) void k_scan2(const int* __restrict__ partials, int* __restrict__ poff,
                                               int* __restrict__ row_ptr) {
  __shared__ int w0s;
  int tid = threadIdx.x;
  int v = (tid < SCAN_BLK) ? partials[tid] : 0;
  int sc = v;
#pragma unroll
  for (int off = 1; off < 64; off <<= 1) {
    int u = __shfl_up(sc, off, 64);
    if ((tid & 63) >= off) sc += u;
  }
  if (tid == 63) w0s = sc;
  __syncthreads();
  int incl = sc + ((tid >= 64) ? w0s : 0);
  if (tid < SCAN_BLK) poff[tid] = incl - v;
  if (tid == 127) row_ptr[N_NODES] = incl;  // == N_EDGES
}

// adds block offsets; writes both row_ptr (in place) and cursor copy
__global__ __launch_bounds__(256) void k_scan3(int* __restrict__ row_ptr, const int* __restrict__ poff,
                                               int* __restrict__ cursor) {
  int tid = threadIdx.x;
  int base = blockIdx.x * 1024 + tid * 4;
  int p = poff[blockIdx.x];
  if (base + 3 < N_NODES) {
    int4 v = *(int4*)(row_ptr + base);
    v.x += p; v.y += p; v.z += p; v.w += p;
    *(int4*)(row_ptr + base) = v;
    *(int4*)(cursor + base) = v;
  } else {
    for (int k = 0; k < 4; ++k)
      if (base + k < N_NODES) {
        int t = row_ptr[base + k] + p;
        row_ptr[base + k] = t;
        cursor[base + k] = t;
      }
  }
}

// ---------------- CSR fill ----------------
__global__ __launch_bounds__(256) void k_fill_csr(const int* __restrict__ src, const int* __restrict__ dst,
                                                  int* __restrict__ cursor, int* __restrict__ csr_src) {
  int i = blockIdx.x * 256 + threadIdx.x;
  if (i < N_EDGES) {
    int d = dst[i];
    int pos = atomicAdd(&cursor[d], 1);
    csr_src[pos] = src[i];
  }
}

// ---------------- embedding lookup ----------------
__global__ __launch_bounds__(256) void k_embed(const int* __restrict__ h, const float* __restrict__ emb,
                                               float* __restrict__ x) {
  int i = blockIdx.x * 256 + threadIdx.x;  // over N*32 float4
  const int total = N_NODES * (HID / 4);
  if (i < total) {
    int r = i >> 5, c = i & 31;
    ((float4*)x)[i] = ((const float4*)emb)[h[r] * (HID / 4) + c];
  }
}

// ---------------- aggregation ----------------
// 16 lanes per node, 2 float4 per lane, edge loop unrolled x4 -> 8 independent 16B gathers in flight
__global__ __launch_bounds__(256) void k_agg(const float* __restrict__ x, const int* __restrict__ row_ptr,
                                             const int* __restrict__ csr_src, const float* __restrict__ norm_src,
                                             const float* __restrict__ norm_dst, float* __restrict__ agg) {
  int node = blockIdx.x * 16 + (threadIdx.x >> 4);
  int l16 = threadIdx.x & 15;
  if (node >= N_NODES) return;
  int s0 = row_ptr[node], s1 = row_ptr[node + 1];
  float ax = 0.f, ay = 0.f, az = 0.f, aw = 0.f;
  float bx = 0.f, by = 0.f, bz = 0.f, bw = 0.f;
  int i = s0;
  for (; i + 3 < s1; i += 4) {
    int sa = csr_src[i], sb = csr_src[i + 1], sc = csr_src[i + 2], sd = csr_src[i + 3];
    float na = norm_src[sa], nb = norm_src[sb], nc = norm_src[sc], nd2 = norm_src[sd];
    const float4* pa = (const float4*)(x + (size_t)sa * HID);
    const float4* pb = (const float4*)(x + (size_t)sb * HID);
    const float4* pc = (const float4*)(x + (size_t)sc * HID);
    const float4* pd = (const float4*)(x + (size_t)sd * HID);
    float4 va0 = pa[l16], va1 = pa[l16 + 16];
    float4 vb0 = pb[l16], vb1 = pb[l16 + 16];
    float4 vc0 = pc[l16], vc1 = pc[l16 + 16];
    float4 vd0 = pd[l16], vd1 = pd[l16 + 16];
    ax += va0.x * na + vb0.x * nb + vc0.x * nc + vd0.x * nd2;
    ay += va0.y * na + vb0.y * nb + vc0.y * nc + vd0.y * nd2;
    az += va0.z * na + vb0.z * nb + vc0.z * nc + vd0.z * nd2;
    aw += va0.w * na + vb0.w * nb + vc0.w * nc + vd0.w * nd2;
    bx += va1.x * na + vb1.x * nb + vc1.x * nc + vd1.x * nd2;
    by += va1.y * na + vb1.y * nb + vc1.y * nc + vd1.y * nd2;
    bz += va1.z * na + vb1.z * nb + vc1.z * nc + vd1.z * nd2;
    bw += va1.w * na + vb1.w * nb + vc1.w * nc + vd1.w * nd2;
  }
  for (; i < s1; ++i) {
    int sa = csr_src[i];
    float na = norm_src[sa];
    const float4* pa = (const float4*)(x + (size_t)sa * HID);
    float4 va0 = pa[l16], va1 = pa[l16 + 16];
    ax += va0.x * na; ay += va0.y * na; az += va0.z * na; aw += va0.w * na;
    bx += va1.x * na; by += va1.y * na; bz += va1.z * na; bw += va1.w * na;
  }
  float nd = norm_dst[node];
  float4 o0 = {ax * nd, ay * nd, az * nd, aw * nd};
  float4 o1 = {bx * nd, by * nd, bz * nd, bw * nd};
  float4* op = (float4*)(agg + (size_t)node * HID);
  op[l16] = o0;
  op[l16 + 16] = o1;
}

// ---------------- GEMM [N,128]x[128,128] + bias + fused BN stats ----------------
// 128x128 tile, 512 threads, thread (tr 0..31, tc 0..15) owns rows tr*4..+3, cols {tc*4..+3, 64+tc*4..+3}.
// acc[4][8] = 32 VGPRs -> no AGPR spill. LDS 33 KB. All LDS reads <=2-way conflict.
__global__ __launch_bounds__(512, 2) void k_gemm_stats(const float* __restrict__ A, const float* __restrict__ W,
                                                       const float* __restrict__ bias, float* __restrict__ Y,
                                                       float* __restrict__ sums, float* __restrict__ sumsq) {
  __shared__ float smem[32 * 132 + 32 * 128];  // 33792 B
  float* sA = smem;             // A^T [kk][row], stride 132
  float* sW = smem + 32 * 132;  // W [kk][col], stride 128
  const int tid = threadIdx.x;
  const int tc = tid & 15, tr = tid >> 4;  // tr 0..31
  const int row0 = blockIdx.x * 128;

  float acc[4][8];
#pragma unroll
  for (int i = 0; i < 4; ++i)
#pragma unroll
    for (int j = 0; j < 8; ++j) acc[i][j] = 0.f;

  for (int kb = 0; kb < 4; ++kb) {
    // stage A^T: 128 rows x 32 k (1024 float4, transpose-store)
#pragma unroll
    for (int it = 0; it < 2; ++it) {
      int idx = tid + it * 512;        // 0..1023
      int r = idx >> 3, c4 = idx & 7;  // row, k-float4
      float4 v = {0.f, 0.f, 0.f, 0.f};
      if (row0 + r < N_NODES) v = *(const float4*)(A + (size_t)(row0 + r) * HID + kb * 32 + c4 * 4);
      sA[(c4 * 4 + 0) * 132 + r] = v.x;
      sA[(c4 * 4 + 1) * 132 + r] = v.y;
      sA[(c4 * 4 + 2) * 132 + r] = v.z;
      sA[(c4 * 4 + 3) * 132 + r] = v.w;
    }
    // stage W: 32 k x 128 cols
#pragma unroll
    for (int it = 0; it < 2; ++it) {
      int idx = tid + it * 512;
      int kk = idx >> 5, c4 = idx & 31;
      *(float4*)(sW + kk * 128 + c4 * 4) = *(const float4*)(W + (size_t)(kb * 32 + kk) * HID + c4 * 4);
    }
    __syncthreads();
#pragma unroll 8
    for (int kk = 0; kk < 32; ++kk) {
      float4 a0 = *(const float4*)(sA + kk * 132 + tr * 4);
      float4 w0 = *(const float4*)(sW + kk * 128 + tc * 4);
      float4 w1 = *(const float4*)(sW + kk * 128 + 64 + tc * 4);
      float a[4] = {a0.x, a0.y, a0.z, a0.w};
      float w[8] = {w0.x, w0.y, w0.z, w0.w, w1.x, w1.y, w1.z, w1.w};
#pragma unroll
      for (int i = 0; i < 4; ++i)
#pragma unroll
        for (int j = 0; j < 8; ++j) acc[i][j] += a[i] * w[j];
    }
    __syncthreads();
  }

  // bias + store + per-thread stats
  float bv[8];
#pragma unroll
  for (int j = 0; j < 8; ++j) bv[j] = bias[(j < 4) ? (tc * 4 + j) : (64 + tc * 4 + j - 4)];
  float s[8], q[8];
#pragma unroll
  for (int j = 0; j < 8; ++j) { s[j] = 0.f; q[j] = 0.f; }
#pragma unroll
  for (int i = 0; i < 4; ++i) {
    int r = row0 + tr * 4 + i;
    if (r < N_NODES) {
      float yv[8];
#pragma unroll
      for (int j = 0; j < 8; ++j) {
        yv[j] = acc[i][j] + bv[j];
        s[j] += yv[j];
        q[j] += yv[j] * yv[j];
      }
      *(float4*)(Y + (size_t)r * HID + tc * 4) = make_float4(yv[0], yv[1], yv[2], yv[3]);
      *(float4*)(Y + (size_t)r * HID + 64 + tc * 4) = make_float4(yv[4], yv[5], yv[6], yv[7]);
    }
  }
  // block reduction over tr (reuse smem: red_s [32][128], red_q [32][128] -> 32 KB)
  __syncthreads();
  float* red_s = smem;
  float* red_q = smem + 4096;
#pragma unroll
  for (int j = 0; j < 8; ++j) {
    int c = (j < 4) ? (tc * 4 + j) : (64 + tc * 4 + j - 4);
    red_s[tr * 128 + c] = s[j];
    red_q[tr * 128 + c] = q[j];
  }
  __syncthreads();
  for (int hh = 16; hh >= 1; hh >>= 1) {
    if (tr < hh) {
#pragma unroll
      for (int j = 0; j < 8; ++j) {
        int c = (j < 4) ? (tc * 4 + j) : (64 + tc * 4 + j - 4);
        red_s[tr * 128 + c] += red_s[(tr + hh) * 128 + c];
        red_q[tr * 128 + c] += red_q[(tr + hh) * 128 + c];
      }
    }
    __syncthreads();
  }
  if (tr == 0) {
#pragma unroll
    for (int j = 0; j < 8; ++j) {
      int c = (j < 4) ? (tc * 4 + j) : (64 + tc * 4 + j - 4);
      atomicAdd(&sums[c], red_s[c]);
      atomicAdd(&sumsq[c], red_q[c]);
    }
  }
}

// ---------------- BN finalize ----------------
__global__ __launch_bounds__(128) void k_bn_final(const float* __restrict__ sums, const float* __restrict__ sumsq,
                                                  const float* __restrict__ gamma, const float* __restrict__ beta,
                                                  float* __restrict__ scale, float* __restrict__ shift) {
  int d = threadIdx.x;
  float mu = sums[d] / (float)N_NODES;
  float var = sumsq[d] / (float)N_NODES - mu * mu;
  float sc = gamma[d] * rsqrtf(var + EPSV);
  scale[d] = sc;
  shift[d] = beta[d] - mu * sc;
}

// ---------------- BN apply + relu + residual (x updated in place) ----------------
__global__ __launch_bounds__(256) void k_bn_apply(const float* __restrict__ Y, const float* __restrict__ scale,
                                                  const float* __restrict__ shift, float* __restrict__ x) {
  int i = blockIdx.x * 256 + threadIdx.x;  // over N*32 float4
  const int total = N_NODES * (HID / 4);
  if (i >= total) return;
  int c4 = i & 31;
  float4 y = ((const float4*)Y)[i];
  float4 sc = ((const float4*)scale)[c4];
  float4 sh = ((const float4*)shift)[c4];
  float4 xv = ((const float4*)x)[i];
  float4 o;
  o.x = fmaxf(y.x * sc.x + sh.x, 0.f) + xv.x;
  o.y = fmaxf(y.y * sc.y + sh.y, 0.f) + xv.y;
  o.z = fmaxf(y.z * sc.z + sh.z, 0.f) + xv.z;
  o.w = fmaxf(y.w * sc.w + sh.w, 0.f) + xv.w;
  ((float4*)x)[i] = o;
}

// ---------------- small dense layers (thread-per-row) ----------------
template <int K, int NOUT, bool RELU>
__global__ __launch_bounds__(256) void k_mlp(const float* __restrict__ X, const float* __restrict__ Wm,
                                             const float* __restrict__ bias, float* __restrict__ Y) {
  __shared__ float Ws[K * NOUT];
  __shared__ float bs[NOUT];
  for (int i = threadIdx.x; i < K * NOUT; i += 256) Ws[i] = Wm[i];
  for (int i = threadIdx.x; i < NOUT; i += 256) bs[i] = bias[i];
  __syncthreads();
  int r = blockIdx.x * 256 + threadIdx.x;
  if (r >= N_NODES) return;
  const float4* xr = (const float4*)(X + (size_t)r * K);
  float acc[NOUT];
#pragma unroll
  for (int c = 0; c < NOUT; ++c) acc[c] = bs[c];
  for (int k4 = 0; k4 < K / 4; ++k4) {
    float4 xv = xr[k4];
    float xs[4] = {xv.x, xv.y, xv.z, xv.w};
#pragma unroll
    for (int kk = 0; kk < 4; ++kk) {
#pragma unroll
      for (int c = 0; c < NOUT; ++c) acc[c] += xs[kk] * Ws[(k4 * 4 + kk) * NOUT + c];
    }
  }
  float* yr = Y + (size_t)r * NOUT;
#pragma unroll
  for (int c = 0; c < NOUT; ++c) yr[c] = RELU ? fmaxf(acc[c], 0.f) : acc[c];
}

extern "C" void kernel_launch(void* const* d_in, const int* in_sizes, int n_in,
                              void* d_out, int out_size, void* d_ws, size_t ws_size,
                              hipStream_t stream) {
  const int* h = (const int*)d_in[0];
  const int* src = (const int*)d_in[1];
  const int* dst = (const int*)d_in[2];
  const float* emb = (const float*)d_in[3];
  const float* W = (const float*)d_in[4];
  const float* b = (const float*)d_in[5];
  const float* gamma = (const float*)d_in[6];
  const float* beta = (const float*)d_in[7];
  const float* W1 = (const float*)d_in[8];
  const float* b1 = (const float*)d_in[9];
  const float* W2 = (const float*)d_in[10];
  const float* b2 = (const float*)d_in[11];
  const float* W3 = (const float*)d_in[12];
  const float* b3 = (const float*)d_in[13];
  float* out = (float*)d_out;

  char* ws = (char*)d_ws;
  size_t off = 0;
  auto alloc = [&](size_t bytes) -> void* {
    void* p = ws + off;
    off += (bytes + 255) & ~(size_t)255;
    return p;
  };
  int* deg_out = (int*)alloc(N_NODES * 4);
  int* deg_in = (int*)alloc(N_NODES * 4);
  float* norm_src = (float*)alloc(N_NODES * 4);
  float* norm_dst = (float*)alloc(N_NODES * 4);
  int* row_ptr = (int*)alloc((N_NODES + 1) * 4);
  int* cursor = (int*)alloc(N_NODES * 4);
  int* csr_src = (int*)alloc((size_t)N_EDGES * 4);
  float* x = (float*)alloc((size_t)N_NODES * HID * 4);
  float* agg = (float*)alloc((size_t)N_NODES * HID * 4);
  float* sums = (float*)alloc(512);
  float* sumsq = (float*)alloc(512);
  float* scale = (float*)alloc(512);
  float* shift = (float*)alloc(512);
  int* partials = (int*)alloc(SCAN_BLK * 4);
  int* poff = (int*)alloc(SCAN_BLK * 4);
  float* y1 = agg;                         // [N,64] reuse (agg dead after layers)
  float* y2 = agg + (size_t)N_NODES * 64;  // [N,32]

  hipMemsetAsync(deg_out, 0, N_NODES * 4, stream);
  hipMemsetAsync(deg_in, 0, N_NODES * 4, stream);
  k_degrees<<<(N_EDGES + 255) / 256, 256, 0, stream>>>(src, dst, deg_out, deg_in);
  k_norms<<<(N_NODES + 255) / 256, 256, 0, stream>>>(deg_out, deg_in, norm_src, norm_dst);
  k_scan1<<<SCAN_BLK, 256, 0, stream>>>(deg_in, row_ptr, partials);
  k_scan2<<<1, 128, 0, stream>>>(partials, poff, row_ptr);
  k_scan3<<<SCAN_BLK, 256, 0, stream>>>(row_ptr, poff, cursor);
  k_fill_csr<<<(N_EDGES + 255) / 256, 256, 0, stream>>>(src, dst, cursor, csr_src);
  k_embed<<<(N_NODES * (HID / 4) + 255) / 256, 256, 0, stream>>>(h, emb, x);

  for (int l = 0; l < N_LAYERS; ++l) {
    k_agg<<<(N_NODES + 15) / 16, 256, 0, stream>>>(x, row_ptr, csr_src, norm_src, norm_dst, agg);
    hipMemsetAsync(sums, 0, 1024, stream);  // sums+sumsq contiguous
    k_gemm_stats<<<(N_NODES + 127) / 128, 512, 0, stream>>>(agg, W + (size_t)l * HID * HID, b + l * HID,
                                                            agg, sums, sumsq);
    k_bn_final<<<1, 128, 0, stream>>>(sums, sumsq, gamma + l * HID, beta + l * HID, scale, shift);
    k_bn_apply<<<(N_NODES * (HID / 4) + 255) / 256, 256, 0, stream>>>(agg, scale, shift, x);
  }

  k_mlp<128, 64, true><<<(N_NODES + 255) / 256, 256, 0, stream>>>(x, W1, b1, y1);
  k_mlp<64, 32, true><<<(N_NODES + 255) / 256, 256, 0, stream>>>(y1, W2, b2, y2);
  k_mlp<32, 6, false><<<(N_NODES + 255) / 256, 256, 0, stream>>>(y2, W3, b3, out);
}

// Round 4
// 887.637 us; speedup vs baseline: 2.6760x; 1.5487x over previous
//
#include <hip/hip_runtime.h>

#define N_NODES 100000
#define N_EDGES 1600000
#define HID 128
#define N_LAYERS 4
#define EPSV 1e-5f
#define SCAN_BLK 98  // ceil(100000/1024)
#define LSTR 40      // LDS row stride in shorts (80B: 16B-aligned, 2-way-max bank conflicts = free)

using f32x4 = __attribute__((ext_vector_type(4))) float;
using s16x8 = __attribute__((ext_vector_type(8))) short;

__device__ __forceinline__ unsigned short f2bf(float f) {
  union { float f; unsigned u; } c{f};
  unsigned u = c.u;
  return (unsigned short)((u + 0x7fffu + ((u >> 16) & 1u)) >> 16);
}
__device__ __forceinline__ float bf2f(unsigned short s) {
  union { unsigned u; float f; } c{(unsigned)s << 16};
  return c.f;
}

// ---------------- degree + norm ----------------
__global__ __launch_bounds__(256) void k_degrees(const int* __restrict__ src, const int* __restrict__ dst,
                                                 int* __restrict__ deg_out, int* __restrict__ deg_in) {
  int i = blockIdx.x * 256 + threadIdx.x;
  if (i < N_EDGES) {
    atomicAdd(&deg_out[src[i]], 1);
    atomicAdd(&deg_in[dst[i]], 1);
  }
}

__global__ __launch_bounds__(256) void k_norms(const int* __restrict__ deg_out, const int* __restrict__ deg_in,
                                               float* __restrict__ norm_src, float* __restrict__ norm_dst) {
  int i = blockIdx.x * 256 + threadIdx.x;
  if (i < N_NODES) {
    int d_o = deg_out[i], d_i = deg_in[i];
    norm_src[i] = d_o > 0 ? rsqrtf((float)d_o) : 0.f;
    norm_dst[i] = d_i > 0 ? rsqrtf((float)d_i) : 0.f;
  }
}

// ---------------- 3-kernel exclusive scan ----------------
__global__ __launch_bounds__(256) void k_scan1(const int* __restrict__ in, int* __restrict__ out,
                                               int* __restrict__ partials) {
  __shared__ int wsum[4];
  int tid = threadIdx.x;
  int base = blockIdx.x * 1024 + tid * 4;
  int4 v = {0, 0, 0, 0};
  if (base + 3 < N_NODES) v = *(const int4*)(in + base);
  else {
    if (base + 0 < N_NODES) v.x = in[base + 0];
    if (base + 1 < N_NODES) v.y = in[base + 1];
    if (base + 2 < N_NODES) v.z = in[base + 2];
    if (base + 3 < N_NODES) v.w = in[base + 3];
  }
  int s4 = v.x + v.y + v.z + v.w;
  int lane = tid & 63, wid = tid >> 6;
  int sc = s4;
#pragma unroll
  for (int off = 1; off < 64; off <<= 1) {
    int u = __shfl_up(sc, off, 64);
    if (lane >= off) sc += u;
  }
  if (lane == 63) wsum[wid] = sc;
  __syncthreads();
  int woff = 0;
#pragma unroll
  for (int w = 0; w < 4; ++w) woff += (w < wid) ? wsum[w] : 0;
  int excl = woff + sc - s4;
  int4 o;
  o.x = excl; o.y = o.x + v.x; o.z = o.y + v.y; o.w = o.z + v.z;
  if (base + 3 < N_NODES) *(int4*)(out + base) = o;
  else {
    if (base + 0 < N_NODES) out[base + 0] = o.x;
    if (base + 1 < N_NODES) out[base + 1] = o.y;
    if (base + 2 < N_NODES) out[base + 2] = o.z;
    if (base + 3 < N_NODES) out[base + 3] = o.w;
  }
  if (tid == 255) partials[blockIdx.x] = woff + sc;
}

__global__ __launch_bounds__(128) void k_scan2(const int* __restrict__ partials, int* __restrict__ poff,
                                               int* __restrict__ row_ptr) {
  __shared__ int w0s;
  int tid = threadIdx.x;
  int v = (tid < SCAN_BLK) ? partials[tid] : 0;
  int sc = v;
#pragma unroll
  for (int off = 1; off < 64; off <<= 1) {
    int u = __shfl_up(sc, off, 64);
    if ((tid & 63) >= off) sc += u;
  }
  if (tid == 63) w0s = sc;
  __syncthreads();
  int incl = sc + ((tid >= 64) ? w0s : 0);
  if (tid < SCAN_BLK) poff[tid] = incl - v;
  if (tid == 127) row_ptr[N_NODES] = incl;
}

__global__ __launch_bounds__(256) void k_scan3(int* __restrict__ row_ptr, const int* __restrict__ poff,
                                               int* __restrict__ cursor) {
  int tid = threadIdx.x;
  int base = blockIdx.x * 1024 + tid * 4;
  int p = poff[blockIdx.x];
  if (base + 3 < N_NODES) {
    int4 v = *(int4*)(row_ptr + base);
    v.x += p; v.y += p; v.z += p; v.w += p;
    *(int4*)(row_ptr + base) = v;
    *(int4*)(cursor + base) = v;
  } else {
    for (int k = 0; k < 4; ++k)
      if (base + k < N_NODES) {
        int t = row_ptr[base + k] + p;
        row_ptr[base + k] = t;
        cursor[base + k] = t;
      }
  }
}

// ---------------- CSR fill ----------------
__global__ __launch_bounds__(256) void k_fill_csr(const int* __restrict__ src, const int* __restrict__ dst,
                                                  int* __restrict__ cursor, int* __restrict__ csr_src) {
  int i = blockIdx.x * 256 + threadIdx.x;
  if (i < N_EDGES) {
    int d = dst[i];
    int pos = atomicAdd(&cursor[d], 1);
    csr_src[pos] = src[i];
  }
}

// ---------------- embedding lookup: writes x (fp32) + xb (bf16) ----------------
__global__ __launch_bounds__(256) void k_embed(const int* __restrict__ h, const float* __restrict__ emb,
                                               float* __restrict__ x, unsigned short* __restrict__ xb) {
  int i = blockIdx.x * 256 + threadIdx.x;  // over N*32 float4
  const int total = N_NODES * (HID / 4);
  if (i < total) {
    int r = i >> 5, c = i & 31;
    float4 v = ((const float4*)emb)[h[r] * (HID / 4) + c];
    ((float4*)x)[i] = v;
    uint2 p;
    p.x = (unsigned)f2bf(v.x) | ((unsigned)f2bf(v.y) << 16);
    p.y = (unsigned)f2bf(v.z) | ((unsigned)f2bf(v.w) << 16);
    *(uint2*)(xb + (size_t)i * 4) = p;
  }
}

// ---------------- W split+transpose: Wt[l][col][k] hi/lo bf16 ----------------
__global__ __launch_bounds__(128) void k_wsplit(const float* __restrict__ W, unsigned short* __restrict__ Wh,
                                                unsigned short* __restrict__ Wl) {
  int l = blockIdx.x >> 7, k = blockIdx.x & 127;
  int c = threadIdx.x;
  float w = W[(size_t)l * HID * HID + k * HID + c];
  unsigned short h = f2bf(w);
  Wh[(size_t)l * HID * HID + c * HID + k] = h;
  Wl[(size_t)l * HID * HID + c * HID + k] = f2bf(w - bf2f(h));
}

// ---------------- aggregation (bf16 gather, fp32 accumulate, hi/lo bf16 output) ----------------
// 16 lanes/node, each lane: 8 contiguous cols (one 16B load per edge). Unroll x4.
__global__ __launch_bounds__(256) void k_agg(const unsigned short* __restrict__ xb, const int* __restrict__ row_ptr,
                                             const int* __restrict__ csr_src, const float* __restrict__ norm_src,
                                             const float* __restrict__ norm_dst,
                                             unsigned short* __restrict__ agg_hi, unsigned short* __restrict__ agg_lo) {
  int node = blockIdx.x * 16 + (threadIdx.x >> 4);
  int l16 = threadIdx.x & 15;
  if (node >= N_NODES) return;
  int s0 = row_ptr[node], s1 = row_ptr[node + 1];
  float acc[8];
#pragma unroll
  for (int j = 0; j < 8; ++j) acc[j] = 0.f;
  int i = s0;
  for (; i + 3 < s1; i += 4) {
#pragma unroll
    for (int e = 0; e < 4; ++e) {
      int s = csr_src[i + e];
      float ns = norm_src[s];
      uint4 u = *(const uint4*)(xb + (size_t)s * HID + l16 * 8);
      unsigned uu[4] = {u.x, u.y, u.z, u.w};
#pragma unroll
      for (int q = 0; q < 4; ++q) {
        union { unsigned u; float f; } lo{uu[q] << 16}, hi{uu[q] & 0xffff0000u};
        acc[q * 2 + 0] += lo.f * ns;
        acc[q * 2 + 1] += hi.f * ns;
      }
    }
  }
  for (; i < s1; ++i) {
    int s = csr_src[i];
    float ns = norm_src[s];
    uint4 u = *(const uint4*)(xb + (size_t)s * HID + l16 * 8);
    unsigned uu[4] = {u.x, u.y, u.z, u.w};
#pragma unroll
    for (int q = 0; q < 4; ++q) {
      union { unsigned u; float f; } lo{uu[q] << 16}, hi{uu[q] & 0xffff0000u};
      acc[q * 2 + 0] += lo.f * ns;
      acc[q * 2 + 1] += hi.f * ns;
    }
  }
  float nd = norm_dst[node];
  unsigned short hh[8], ll[8];
#pragma unroll
  for (int j = 0; j < 8; ++j) {
    float v = acc[j] * nd;
    hh[j] = f2bf(v);
    ll[j] = f2bf(v - bf2f(hh[j]));
  }
  uint4 ho, lo4;
  ho.x = (unsigned)hh[0] | ((unsigned)hh[1] << 16); ho.y = (unsigned)hh[2] | ((unsigned)hh[3] << 16);
  ho.z = (unsigned)hh[4] | ((unsigned)hh[5] << 16); ho.w = (unsigned)hh[6] | ((unsigned)hh[7] << 16);
  lo4.x = (unsigned)ll[0] | ((unsigned)ll[1] << 16); lo4.y = (unsigned)ll[2] | ((unsigned)ll[3] << 16);
  lo4.z = (unsigned)ll[4] | ((unsigned)ll[5] << 16); lo4.w = (unsigned)ll[6] | ((unsigned)ll[7] << 16);
  *(uint4*)(agg_hi + (size_t)node * HID + l16 * 8) = ho;
  *(uint4*)(agg_lo + (size_t)node * HID + l16 * 8) = lo4;
}

// ---------------- MFMA GEMM: Y = A@W + b, A as hi/lo bf16, 3-pass bf16x3 (fp32-grade) ----------------
// 128-row tile, 256 threads (4 waves), wave w owns rows w*32..+31 x all 128 cols.
// acc[2][8] f32x4. Fused BN column stats.
__global__ __launch_bounds__(256, 4) void k_gemm_mfma(const unsigned short* __restrict__ Ah,
                                                      const unsigned short* __restrict__ Al,
                                                      const unsigned short* __restrict__ Bh,
                                                      const unsigned short* __restrict__ Bl,
                                                      const float* __restrict__ bias, float* __restrict__ Y,
                                                      float* __restrict__ sums, float* __restrict__ sumsq) {
  __shared__ unsigned short sAh[128 * LSTR], sAl[128 * LSTR], sBh[128 * LSTR], sBl[128 * LSTR];  // 40960 B
  const int tid = threadIdx.x;
  const int lane = tid & 63, wid = tid >> 6;
  const int l15 = lane & 15, kg = lane >> 4;
  const int row0 = blockIdx.x * 128;

  f32x4 acc[2][8];
#pragma unroll
  for (int mi = 0; mi < 2; ++mi)
#pragma unroll
    for (int ni = 0; ni < 8; ++ni) acc[mi][ni] = (f32x4){0.f, 0.f, 0.f, 0.f};

  for (int kb = 0; kb < 4; ++kb) {
    const int k0 = kb * 32;
    // stage: A(hi,lo) rows 0..127 k-slice [k0,k0+32); B(hi,lo) cols 0..127 same slice.
#pragma unroll
    for (int it = 0; it < 2; ++it) {
      int idx = tid * 2 + it;        // 0..511
      int r = idx >> 2, q = idx & 3; // row/col, 8-short chunk
      int gr = row0 + r;
      s16x8 vh = {0, 0, 0, 0, 0, 0, 0, 0}, vl = {0, 0, 0, 0, 0, 0, 0, 0};
      if (gr < N_NODES) {
        vh = *(const s16x8*)(Ah + (size_t)gr * HID + k0 + q * 8);
        vl = *(const s16x8*)(Al + (size_t)gr * HID + k0 + q * 8);
      }
      *(s16x8*)&sAh[r * LSTR + q * 8] = vh;
      *(s16x8*)&sAl[r * LSTR + q * 8] = vl;
      *(s16x8*)&sBh[r * LSTR + q * 8] = *(const s16x8*)(Bh + (size_t)r * HID + k0 + q * 8);
      *(s16x8*)&sBl[r * LSTR + q * 8] = *(const s16x8*)(Bl + (size_t)r * HID + k0 + q * 8);
    }
    __syncthreads();
    s16x8 afh[2], afl[2];
#pragma unroll
    for (int mi = 0; mi < 2; ++mi) {
      int ar = wid * 32 + mi * 16 + l15;
      afh[mi] = *(const s16x8*)&sAh[ar * LSTR + kg * 8];
      afl[mi] = *(const s16x8*)&sAl[ar * LSTR + kg * 8];
    }
#pragma unroll
    for (int ni = 0; ni < 8; ++ni) {
      int bc = ni * 16 + l15;
      s16x8 bh = *(const s16x8*)&sBh[bc * LSTR + kg * 8];
      s16x8 bl = *(const s16x8*)&sBl[bc * LSTR + kg * 8];
#pragma unroll
      for (int mi = 0; mi < 2; ++mi) {
        acc[mi][ni] = __builtin_amdgcn_mfma_f32_16x16x32_bf16(afh[mi], bh, acc[mi][ni], 0, 0, 0);
        acc[mi][ni] = __builtin_amdgcn_mfma_f32_16x16x32_bf16(afh[mi], bl, acc[mi][ni], 0, 0, 0);
        acc[mi][ni] = __builtin_amdgcn_mfma_f32_16x16x32_bf16(afl[mi], bh, acc[mi][ni], 0, 0, 0);
      }
    }
    __syncthreads();
  }

  // epilogue: bias + store + per-lane column stats
  float bv[8], sp[8], qp[8];
#pragma unroll
  for (int ni = 0; ni < 8; ++ni) {
    bv[ni] = bias[ni * 16 + l15];
    sp[ni] = 0.f; qp[ni] = 0.f;
  }
#pragma unroll
  for (int mi = 0; mi < 2; ++mi) {
    int rbase = row0 + wid * 32 + mi * 16 + kg * 4;
#pragma unroll
    for (int reg = 0; reg < 4; ++reg) {
      int r = rbase + reg;
      if (r < N_NODES) {
        float* yr = Y + (size_t)r * HID;
#pragma unroll
        for (int ni = 0; ni < 8; ++ni) {
          float y = acc[mi][ni][reg] + bv[ni];
          yr[ni * 16 + l15] = y;
          sp[ni] += y;
          qp[ni] += y * y;
        }
      }
    }
  }
  __syncthreads();
  float* red_s = (float*)sAh;  // [16][128] = 8KB (fits in sAh's 10240B)
  float* red_q = (float*)sBh;
  int slot = wid * 4 + kg;
#pragma unroll
  for (int ni = 0; ni < 8; ++ni) {
    red_s[slot * 128 + ni * 16 + l15] = sp[ni];
    red_q[slot * 128 + ni * 16 + l15] = qp[ni];
  }
  __syncthreads();
  if (tid < 128) {
    float a = 0.f, b2 = 0.f;
#pragma unroll
    for (int s = 0; s < 16; ++s) {
      a += red_s[s * 128 + tid];
      b2 += red_q[s * 128 + tid];
    }
    atomicAdd(&sums[tid], a);
    atomicAdd(&sumsq[tid], b2);
  }
}

// ---------------- BN finalize ----------------
__global__ __launch_bounds__(128) void k_bn_final(const float* __restrict__ sums, const float* __restrict__ sumsq,
                                                  const float* __restrict__ gamma, const float* __restrict__ beta,
                                                  float* __restrict__ scale, float* __restrict__ shift) {
  int d = threadIdx.x;
  float mu = sums[d] / (float)N_NODES;
  float var = sumsq[d] / (float)N_NODES - mu * mu;
  float sc = gamma[d] * rsqrtf(var + EPSV);
  scale[d] = sc;
  shift[d] = beta[d] - mu * sc;
}

// ---------------- BN apply + relu + residual; writes x (fp32) + xb (bf16 for next gather) ----------------
__global__ __launch_bounds__(256) void k_bn_apply(const float* __restrict__ Y, const float* __restrict__ scale,
                                                  const float* __restrict__ shift, float* __restrict__ x,
                                                  unsigned short* __restrict__ xb) {
  int i = blockIdx.x * 256 + threadIdx.x;  // over N*32 float4
  const int total = N_NODES * (HID / 4);
  if (i >= total) return;
  int c4 = i & 31;
  float4 y = ((const float4*)Y)[i];
  float4 sc = ((const float4*)scale)[c4];
  float4 sh = ((const float4*)shift)[c4];
  float4 xv = ((const float4*)x)[i];
  float4 o;
  o.x = fmaxf(y.x * sc.x + sh.x, 0.f) + xv.x;
  o.y = fmaxf(y.y * sc.y + sh.y, 0.f) + xv.y;
  o.z = fmaxf(y.z * sc.z + sh.z, 0.f) + xv.z;
  o.w = fmaxf(y.w * sc.w + sh.w, 0.f) + xv.w;
  ((float4*)x)[i] = o;
  uint2 p;
  p.x = (unsigned)f2bf(o.x) | ((unsigned)f2bf(o.y) << 16);
  p.y = (unsigned)f2bf(o.z) | ((unsigned)f2bf(o.w) << 16);
  *(uint2*)(xb + (size_t)i * 4) = p;
}

// ---------------- small dense layers (thread-per-row) ----------------
template <int K, int NOUT, bool RELU>
__global__ __launch_bounds__(256) void k_mlp(const float* __restrict__ X, const float* __restrict__ Wm,
                                             const float* __restrict__ bias, float* __restrict__ Y) {
  __shared__ float Ws[K * NOUT];
  __shared__ float bs[NOUT];
  for (int i = threadIdx.x; i < K * NOUT; i += 256) Ws[i] = Wm[i];
  for (int i = threadIdx.x; i < NOUT; i += 256) bs[i] = bias[i];
  __syncthreads();
  int r = blockIdx.x * 256 + threadIdx.x;
  if (r >= N_NODES) return;
  const float4* xr = (const float4*)(X + (size_t)r * K);
  float acc[NOUT];
#pragma unroll
  for (int c = 0; c < NOUT; ++c) acc[c] = bs[c];
  for (int k4 = 0; k4 < K / 4; ++k4) {
    float4 xv = xr[k4];
    float xs[4] = {xv.x, xv.y, xv.z, xv.w};
#pragma unroll
    for (int kk = 0; kk < 4; ++kk) {
#pragma unroll
      for (int c = 0; c < NOUT; ++c) acc[c] += xs[kk] * Ws[(k4 * 4 + kk) * NOUT + c];
    }
  }
  float* yr = Y + (size_t)r * NOUT;
#pragma unroll
  for (int c = 0; c < NOUT; ++c) yr[c] = RELU ? fmaxf(acc[c], 0.f) : acc[c];
}

extern "C" void kernel_launch(void* const* d_in, const int* in_sizes, int n_in,
                              void* d_out, int out_size, void* d_ws, size_t ws_size,
                              hipStream_t stream) {
  const int* h = (const int*)d_in[0];
  const int* src = (const int*)d_in[1];
  const int* dst = (const int*)d_in[2];
  const float* emb = (const float*)d_in[3];
  const float* W = (const float*)d_in[4];
  const float* b = (const float*)d_in[5];
  const float* gamma = (const float*)d_in[6];
  const float* beta = (const float*)d_in[7];
  const float* W1 = (const float*)d_in[8];
  const float* b1 = (const float*)d_in[9];
  const float* W2 = (const float*)d_in[10];
  const float* b2 = (const float*)d_in[11];
  const float* W3 = (const float*)d_in[12];
  const float* b3 = (const float*)d_in[13];
  float* out = (float*)d_out;

  char* ws = (char*)d_ws;
  size_t off = 0;
  auto alloc = [&](size_t bytes) -> void* {
    void* p = ws + off;
    off += (bytes + 255) & ~(size_t)255;
    return p;
  };
  int* deg_out = (int*)alloc(N_NODES * 4);
  int* deg_in = (int*)alloc(N_NODES * 4);
  float* norm_src = (float*)alloc(N_NODES * 4);
  float* norm_dst = (float*)alloc(N_NODES * 4);
  int* row_ptr = (int*)alloc((N_NODES + 1) * 4);
  int* cursor = (int*)alloc(N_NODES * 4);
  int* csr_src = (int*)alloc((size_t)N_EDGES * 4);
  float* x = (float*)alloc((size_t)N_NODES * HID * 4);
  unsigned short* xb = (unsigned short*)alloc((size_t)N_NODES * HID * 2);
  unsigned short* agg_hi = (unsigned short*)alloc((size_t)N_NODES * HID * 2);
  unsigned short* agg_lo = (unsigned short*)alloc((size_t)N_NODES * HID * 2);
  float* Yb = (float*)alloc((size_t)N_NODES * HID * 4);
  unsigned short* Wh = (unsigned short*)alloc((size_t)N_LAYERS * HID * HID * 2);
  unsigned short* Wl = (unsigned short*)alloc((size_t)N_LAYERS * HID * HID * 2);
  float* sums = (float*)alloc(512);
  float* sumsq = (float*)alloc(512);
  float* scale = (float*)alloc(512);
  float* shift = (float*)alloc(512);
  int* partials = (int*)alloc(SCAN_BLK * 4);
  int* poff = (int*)alloc(SCAN_BLK * 4);
  float* y1 = Yb;                         // [N,64] reuse (Yb dead after layers)
  float* y2 = Yb + (size_t)N_NODES * 64;  // [N,32]

  hipMemsetAsync(deg_out, 0, N_NODES * 4, stream);
  hipMemsetAsync(deg_in, 0, N_NODES * 4, stream);
  k_degrees<<<(N_EDGES + 255) / 256, 256, 0, stream>>>(src, dst, deg_out, deg_in);
  k_norms<<<(N_NODES + 255) / 256, 256, 0, stream>>>(deg_out, deg_in, norm_src, norm_dst);
  k_scan1<<<SCAN_BLK, 256, 0, stream>>>(deg_in, row_ptr, partials);
  k_scan2<<<1, 128, 0, stream>>>(partials, poff, row_ptr);
  k_scan3<<<SCAN_BLK, 256, 0, stream>>>(row_ptr, poff, cursor);
  k_fill_csr<<<(N_EDGES + 255) / 256, 256, 0, stream>>>(src, dst, cursor, csr_src);
  k_embed<<<(N_NODES * (HID / 4) + 255) / 256, 256, 0, stream>>>(h, emb, x, xb);
  k_wsplit<<<N_LAYERS * 128, 128, 0, stream>>>(W, Wh, Wl);

  for (int l = 0; l < N_LAYERS; ++l) {
    k_agg<<<(N_NODES + 15) / 16, 256, 0, stream>>>(xb, row_ptr, csr_src, norm_src, norm_dst, agg_hi, agg_lo);
    hipMemsetAsync(sums, 0, 1024, stream);  // sums+sumsq contiguous
    k_gemm_mfma<<<(N_NODES + 127) / 128, 256, 0, stream>>>(agg_hi, agg_lo,
                                                           Wh + (size_t)l * HID * HID, Wl + (size_t)l * HID * HID,
                                                           b + l * HID, Yb, sums, sumsq);
    k_bn_final<<<1, 128, 0, stream>>>(sums, sumsq, gamma + l * HID, beta + l * HID, scale, shift);
    k_bn_apply<<<(N_NODES * (HID / 4) + 255) / 256, 256, 0, stream>>>(Yb, scale, shift, x, xb);
  }

  k_mlp<128, 64, true><<<(N_NODES + 255) / 256, 256, 0, stream>>>(x, W1, b1, y1);
  k_mlp<64, 32, true><<<(N_NODES + 255) / 256, 256, 0, stream>>>(y1, W2, b2, y2);
  k_mlp<32, 6, false><<<(N_NODES + 255) / 256, 256, 0, stream>>>(y2, W3, b3, out);
}